// Round 3
// baseline (96.189 us; speedup 1.0000x reference)
//
#include <hip/hip_runtime.h>

#define POPN  4096
#define LENN  2048
#define GRIDN 512
#define NWORDS (GRIDN * GRIDN / 32)   // 8192 u32 seen-bitmap (32 KB)
#define TPB   512
#define LCAP  2047                    // worst case extras; LDS total = 40960 B -> 4 blocks/CU

__global__ __launch_bounds__(TPB) void fitness_kernel(
    const float* __restrict__ pop,
    const float* __restrict__ tp,
    float* __restrict__ out)
{
    __shared__ unsigned seen[NWORDS];   // bit set -> code visited at least once
    __shared__ unsigned lcount;
    __shared__ unsigned list[LCAP];     // one entry per extra (2nd+) visit

    const int tid  = threadIdx.x;
    const int path = blockIdx.x;

    // Zero seen bitmap (16B LDS stores) + counter.
    {
        uint4 z = make_uint4(0u, 0u, 0u, 0u);
        uint4* s4 = (uint4*)seen;
        #pragma unroll
        for (int i = tid; i < NWORDS / 4; i += TPB) s4[i] = z;
        if (tid == 0) lcount = 0u;
    }

    const float*  p  = pop + (size_t)path * (LENN * 2);
    const float4* p4 = (const float4*)p;

    // Thread t owns points [4t, 4t+4): two float4 loads.
    float4 a = p4[tid * 2];
    float4 b = p4[tid * 2 + 1];
    float xs[5], ys[5];
    xs[0] = a.x; ys[0] = a.y;
    xs[1] = a.z; ys[1] = a.w;
    xs[2] = b.x; ys[2] = b.y;
    xs[3] = b.z; ys[3] = b.w;

    // Seam point (base+4): neighbor lane's first point via shuffle; lane 63
    // of each wave crosses a wave boundary -> do the 8B load (8 loads/block).
    const int base = tid * 4;
    {
        float nx = __shfl_down(xs[0], 1, 64);
        float ny = __shfl_down(ys[0], 1, 64);
        if ((tid & 63) == 63 && base + 4 < LENN) {
            float2 c = ((const float2*)p)[base + 4];
            nx = c.x; ny = c.y;
        }
        xs[4] = nx; ys[4] = ny;
    }
    const int nsteps = (base + 4 < LENN) ? 4 : 3;

    int code[4];
    #pragma unroll
    for (int j = 0; j < 4; ++j)
        code[j] = (int)xs[j] * GRIDN + (int)ys[j];

    // Random 4B gathers into the 1MB table: non-temporal (L1 no-allocate) --
    // every lane is an L1 miss anyway; avoid the thrash/fill overhead.
    float g[4];
    #pragma unroll
    for (int j = 0; j < 4; ++j)
        g[j] = __builtin_nontemporal_load(&tp[code[j]]);

    __syncthreads();                 // bitmap zeroed (placed after loads issued)

    #pragma unroll
    for (int j = 0; j < 4; ++j) {
        unsigned w   = (unsigned)code[j] >> 5;
        unsigned bit = 1u << (code[j] & 31);
        unsigned old = atomicOr(&seen[w], bit);
        if (old & bit) {                          // 2nd-or-later visit: append
            unsigned idx = atomicAdd(&lcount, 1u);
            if (idx < LCAP) list[idx] = (unsigned)code[j];
        }
    }

    int cont = 0;
    #pragma unroll
    for (int j = 0; j < 4; ++j) {
        if (j < nsteps) {
            float d = fabsf(xs[j + 1] - xs[j]) + fabsf(ys[j + 1] - ys[j]);
            if (d > 1.0f) cont++;
        }
    }

    float reward = (g[0] + g[1]) + (g[2] + g[3]);

    __syncthreads();                 // list + lcount complete

    // n_dup_positions = unique codes in list. k is tiny (~8) for this data.
    int k = (int)lcount; if (k > LCAP) k = LCAP;
    int dupc = 0;
    for (int i = tid; i < k; i += TPB) {
        unsigned c = list[i];
        bool first = true;
        for (int j = 0; j < i; ++j)
            if (list[j] == c) { first = false; break; }
        if (first) dupc++;
    }

    float fit = reward - 0.5f * (float)cont - 0.2f * (float)dupc;

    // Wave shuffle reduce; partials into seen[0..7] (dead after atomics barrier).
    #pragma unroll
    for (int off = 32; off > 0; off >>= 1)
        fit += __shfl_down(fit, off, 64);

    float* scratch = (float*)seen;
    if ((tid & 63) == 0) scratch[tid >> 6] = fit;
    __syncthreads();
    if (tid == 0) {
        float s = 0.0f;
        #pragma unroll
        for (int w2 = 0; w2 < TPB / 64; ++w2) s += scratch[w2];
        out[path] = s;
    }
}

extern "C" void kernel_launch(void* const* d_in, const int* in_sizes, int n_in,
                              void* d_out, int out_size, void* d_ws, size_t ws_size,
                              hipStream_t stream) {
    const float* pop = (const float*)d_in[0];   // [POP, LEN, 2] f32
    const float* tp  = (const float*)d_in[1];   // [GRID, GRID] f32
    float* out = (float*)d_out;                 // [POP] f32
    (void)in_sizes; (void)n_in; (void)out_size; (void)d_ws; (void)ws_size;

    fitness_kernel<<<POPN, TPB, 0, stream>>>(pop, tp, out);
}

// Round 4
// 44.203 us; speedup vs baseline: 2.1761x; 2.1761x over previous
//
#include <hip/hip_runtime.h>

#define POPN  4096
#define LENN  2048
#define GRIDN 512
#define NWORDS (GRIDN * GRIDN / 32)   // 8192 u32 seen-bitmap (32 KB)
#define TPB   512
#define LCAP  2047                    // worst-case extras; LDS total = 40960 B -> 4 blocks/CU

__global__ __launch_bounds__(TPB) void fitness_kernel(
    const float* __restrict__ pop,
    const float* __restrict__ tp,
    float* __restrict__ out)
{
    __shared__ unsigned seen[NWORDS];   // bit set -> code visited at least once
    __shared__ unsigned lcount;
    __shared__ unsigned list[LCAP];     // one entry per extra (2nd+) visit

    const int tid  = threadIdx.x;
    const int path = blockIdx.x;

    // Zero seen bitmap (16B LDS stores) + counter.
    {
        uint4 z = make_uint4(0u, 0u, 0u, 0u);
        uint4* s4 = (uint4*)seen;
        #pragma unroll
        for (int i = tid; i < NWORDS / 4; i += TPB) s4[i] = z;
        if (tid == 0) lcount = 0u;
    }

    const float*  p  = pop + (size_t)path * (LENN * 2);
    const float4* p4 = (const float4*)p;

    // Thread t owns points [4t, 4t+4): two float4 loads.
    float4 a = p4[tid * 2];
    float4 b = p4[tid * 2 + 1];
    float xs[5], ys[5];
    xs[0] = a.x; ys[0] = a.y;
    xs[1] = a.z; ys[1] = a.w;
    xs[2] = b.x; ys[2] = b.y;
    xs[3] = b.z; ys[3] = b.w;

    // Seam point (base+4): neighbor lane's first point via shuffle; lane 63
    // of each wave crosses a wave boundary -> do the 8B load (8 loads/block).
    const int base = tid * 4;
    {
        float nx = __shfl_down(xs[0], 1, 64);
        float ny = __shfl_down(ys[0], 1, 64);
        if ((tid & 63) == 63 && base + 4 < LENN) {
            float2 c = ((const float2*)p)[base + 4];
            nx = c.x; ny = c.y;
        }
        xs[4] = nx; ys[4] = ny;
    }
    const int nsteps = (base + 4 < LENN) ? 4 : 3;

    int code[4];
    #pragma unroll
    for (int j = 0; j < 4; ++j)
        code[j] = (int)xs[j] * GRIDN + (int)ys[j];

    // Random 4B gathers into the L2-resident 1MB table. sc0 = SE-scope load:
    // bypasses L1 allocation (every lane is an L1 miss anyway), served by L2.
    float g0, g1, g2, g3;
    {
        const float* a0 = tp + code[0];
        const float* a1 = tp + code[1];
        const float* a2 = tp + code[2];
        const float* a3 = tp + code[3];
        asm volatile(
            "global_load_dword %0, %4, off sc0\n\t"
            "global_load_dword %1, %5, off sc0\n\t"
            "global_load_dword %2, %6, off sc0\n\t"
            "global_load_dword %3, %7, off sc0\n\t"
            "s_waitcnt vmcnt(0)"
            : "=&v"(g0), "=&v"(g1), "=&v"(g2), "=&v"(g3)
            : "v"(a0), "v"(a1), "v"(a2), "v"(a3)
            : "memory");
    }

    __syncthreads();                 // bitmap zeroed

    #pragma unroll
    for (int j = 0; j < 4; ++j) {
        unsigned w   = (unsigned)code[j] >> 5;
        unsigned bit = 1u << (code[j] & 31);
        unsigned old = atomicOr(&seen[w], bit);
        if (old & bit) {                          // 2nd-or-later visit: append
            unsigned idx = atomicAdd(&lcount, 1u);
            if (idx < LCAP) list[idx] = (unsigned)code[j];
        }
    }

    int cont = 0;
    #pragma unroll
    for (int j = 0; j < 4; ++j) {
        if (j < nsteps) {
            float d = fabsf(xs[j + 1] - xs[j]) + fabsf(ys[j + 1] - ys[j]);
            if (d > 1.0f) cont++;
        }
    }

    float reward = (g0 + g1) + (g2 + g3);

    __syncthreads();                 // list + lcount complete

    // n_dup_positions = unique codes in list. k is tiny (~8) for this data.
    int k = (int)lcount; if (k > LCAP) k = LCAP;
    int dupc = 0;
    for (int i = tid; i < k; i += TPB) {
        unsigned c = list[i];
        bool first = true;
        for (int j = 0; j < i; ++j)
            if (list[j] == c) { first = false; break; }
        if (first) dupc++;
    }

    float fit = reward - 0.5f * (float)cont - 0.2f * (float)dupc;

    // Wave shuffle reduce; partials into seen[0..7] (dead after atomics barrier).
    #pragma unroll
    for (int off = 32; off > 0; off >>= 1)
        fit += __shfl_down(fit, off, 64);

    float* scratch = (float*)seen;
    if ((tid & 63) == 0) scratch[tid >> 6] = fit;
    __syncthreads();
    if (tid == 0) {
        float s = 0.0f;
        #pragma unroll
        for (int w2 = 0; w2 < TPB / 64; ++w2) s += scratch[w2];
        out[path] = s;
    }
}

extern "C" void kernel_launch(void* const* d_in, const int* in_sizes, int n_in,
                              void* d_out, int out_size, void* d_ws, size_t ws_size,
                              hipStream_t stream) {
    const float* pop = (const float*)d_in[0];   // [POP, LEN, 2] f32
    const float* tp  = (const float*)d_in[1];   // [GRID, GRID] f32
    float* out = (float*)d_out;                 // [POP] f32
    (void)in_sizes; (void)n_in; (void)out_size; (void)d_ws; (void)ws_size;

    fitness_kernel<<<POPN, TPB, 0, stream>>>(pop, tp, out);
}